// Round 2
// baseline (106.506 us; speedup 1.0000x reference)
//
#include <hip/hip_runtime.h>
#include <math.h>

#define N_ 256
#define C_ 100
#define D_ 512

__device__ inline float waveReduceSum(float v) {
    #pragma unroll
    for (int off = 32; off > 0; off >>= 1) v += __shfl_xor(v, off, 64);
    return v;
}
__device__ inline float waveReduceMax(float v) {
    #pragma unroll
    for (int off = 32; off > 0; off >>= 1) v = fmaxf(v, __shfl_xor(v, off, 64));
    return v;
}
__device__ inline float clip1(float x) { return fminf(fmaxf(x, -1.0f), 1.0f); }

// K1: row norms only. rn[r] = 3 / max(||row||, 1e-12). rows 0..255 = X, 256..355 = P.
// Grid 89 x 256 (wave per row).
__global__ void norms_kernel(const float* __restrict__ X,
                             const float* __restrict__ P,
                             float* __restrict__ rn) {
    int w = threadIdx.x >> 6, lane = threadIdx.x & 63;
    int r = blockIdx.x * 4 + w;            // [0, 356)
    const float* src = (r < N_) ? (X + (size_t)r * D_) : (P + (size_t)(r - N_) * D_);
    const float4* s4 = (const float4*)src;
    float4 a = s4[lane], b = s4[lane + 64];
    float ss = a.x*a.x + a.y*a.y + a.z*a.z + a.w*a.w
             + b.x*b.x + b.y*b.y + b.z*b.z + b.w*b.w;
    ss = waveReduceSum(ss);
    if (lane == 0) rn[r] = 3.0f / fmaxf(sqrtf(ss), 1e-12f);
}

// K2: all dot products, one wave each, scaled by rn in the epilogue.
//   wid < 25600          : IP[i,p] = rn[i]*rn[256+p] * (X_i . P_p)
//   wid >= 25600         : q = wid-25600; d = (q>>8)+1; i1 = q&255; i2 = i1+d
//                          G[i1,i2] = rn[i1]*rn[i2] * (X_i1 . X_i2)  (cross-class upper only)
// Grid 22720 x 256 (4 waves/block), 90880 waves.
__global__ void dots_kernel(const float* __restrict__ X,
                            const float* __restrict__ P,
                            const float* __restrict__ rn,
                            const int* __restrict__ T,
                            float* __restrict__ IP,
                            float* __restrict__ G) {
    int wid = blockIdx.x * 4 + (threadIdx.x >> 6);
    int lane = threadIdx.x & 63;
    const float *arow, *brow;
    float scale;
    float* dst;
    if (wid < 25600) {
        int i = wid / 100, p = wid - i * 100;
        arow = X + (size_t)i * D_;
        brow = P + (size_t)p * D_;
        scale = rn[i] * rn[N_ + p];
        dst = IP + wid;                    // wid == i*100 + p
    } else {
        int q = wid - 25600;
        int d = (q >> 8) + 1, i1 = q & 255;
        int i2 = i1 + d;
        if (i2 >= N_) return;              // wave-uniform exit, no barriers in kernel
        if (T[i1] == T[i2]) return;        // same-class pair never consumed
        arow = X + (size_t)i1 * D_;
        brow = X + (size_t)i2 * D_;
        scale = rn[i1] * rn[i2];
        dst = G + (size_t)i1 * N_ + i2;
    }
    const float4* a4 = (const float4*)arow;
    const float4* b4 = (const float4*)brow;
    float acc = 0.0f;
    #pragma unroll
    for (int k = 0; k < 2; ++k) {
        float4 av = a4[lane + 64*k], bv = b4[lane + 64*k];
        acc += av.x*bv.x + av.y*bv.y + av.z*bv.z + av.w*bv.w;
    }
    acc = waveReduceSum(acc);
    if (lane == 0) *dst = acc * scale;
}

// K3: fused pair-loss + real-loss.
//   blocks [0, 16384): wave per pair pid = blk*4+w; i1=pid>>8, i2=pid&255
//   blocks [16384, 16448): wave per real row i = (blk-16384)*4+w
__global__ void pair_real_kernel(const float* __restrict__ IP,
                                 const float* __restrict__ G,
                                 const int* __restrict__ T,
                                 float* __restrict__ psum,
                                 float* __restrict__ loss_real) {
    int w = threadIdx.x >> 6, lane = threadIdx.x & 63;
    int blk = blockIdx.x;
    if (blk < 16384) {
        int pid = blk * 4 + w;
        int i1 = pid >> 8, i2 = pid & 255;
        float contrib = 0.0f;
        if (i2 > i1) {
            int t1 = T[i1], t2 = T[i2];
            if (t1 != t2) {
                const float* ip1 = IP + (size_t)i1 * C_;
                const float* ip2 = IP + (size_t)i2 * C_;
                float g = G[(size_t)i1 * N_ + i2];
                float X1P1 = clip1(ip1[t1]);
                float X1P2 = clip1(ip1[t2]);
                float X2P1 = clip1(ip2[t1]);
                float X2P2 = clip1(ip2[t2]);
                float num = X2P2 - X2P1;
                float den = num + X1P1 - X1P2;
                float lam = fminf(fmaxf(num / den, 0.3f), 0.7f);
                float oml = 1.0f - lam;
                float wn2 = 9.0f * (lam*lam + oml*oml) + 2.0f * lam * oml * g;
                float s = 3.0f / fmaxf(sqrtf(fmaxf(wn2, 0.0f)), 1e-12f);
                float s2 = 2.0f * s;
                float e_a = s2 * (lam * ip1[lane] + oml * ip2[lane]);
                bool vb = lane < (C_ - 64);
                float e_b = vb ? s2 * (lam * ip1[lane+64] + oml * ip2[lane+64]) : -INFINITY;
                float mx = waveReduceMax(fmaxf(e_a, e_b));
                float sum = expf(e_a - mx) + (vb ? expf(e_b - mx) : 0.0f);
                sum = waveReduceSum(sum);
                float LSE = mx + logf(sum);
                float ec1 = (t1 < 64) ? __shfl(e_a, t1, 64) : __shfl(e_b, t1 - 64, 64);
                float ec2 = (t2 < 64) ? __shfl(e_a, t2, 64) : __shfl(e_b, t2 - 64, 64);
                contrib = LSE - lam * ec1 - oml * ec2;
            }
        }
        __shared__ float ssum[4];
        if (lane == 0) ssum[w] = contrib;
        __syncthreads();
        if (threadIdx.x == 0) psum[blk] = ssum[0] + ssum[1] + ssum[2] + ssum[3];
    } else {
        int i = (blk - 16384) * 4 + w;     // [0, 256)
        const float* ip = IP + (size_t)i * C_;
        float e_a = 2.0f * ip[lane];
        bool vb = lane < (C_ - 64);
        float e_b = vb ? 2.0f * ip[lane+64] : -INFINITY;
        float mx = waveReduceMax(fmaxf(e_a, e_b));
        float sum = expf(e_a - mx) + (vb ? expf(e_b - mx) : 0.0f);
        sum = waveReduceSum(sum);
        float LSE = mx + logf(sum);
        if (lane == 0) loss_real[i] = LSE - 2.0f * ip[T[i]];
    }
}

// K4: final reduce. 1 block x 256. Pair count via class histogram:
// diff_count = 32640 - sum_c n_c(n_c-1)/2.
__global__ void finalize_kernel(const float* __restrict__ psum,
                                const float* __restrict__ loss_real,
                                const int* __restrict__ T,
                                float* __restrict__ out) {
    __shared__ int hist[C_];
    int t = threadIdx.x;
    if (t < C_) hist[t] = 0;
    __syncthreads();
    atomicAdd(&hist[T[t]], 1);
    __syncthreads();
    float a = loss_real[t];
    for (int k = t; k < 16384; k += 256) a += psum[k];
    float same = 0.0f;
    if (t < C_) { float n = (float)hist[t]; same = 0.5f * n * (n - 1.0f); }
    float ra = waveReduceSum(a), rs = waveReduceSum(same);
    __shared__ float s1[4], s2[4];
    int w = t >> 6, lane = t & 63;
    if (lane == 0) { s1[w] = ra; s2[w] = rs; }
    __syncthreads();
    if (t == 0) {
        float tot = s1[0] + s1[1] + s1[2] + s1[3];
        float sm  = s2[0] + s2[1] + s2[2] + s2[3];
        float cnt = (float)N_ + (32640.0f - sm);
        out[0] = tot / cnt;
    }
}

extern "C" void kernel_launch(void* const* d_in, const int* in_sizes, int n_in,
                              void* d_out, int out_size, void* d_ws, size_t ws_size,
                              hipStream_t stream) {
    const float* X = (const float*)d_in[0];   // (256, 512) f32
    const float* P = (const float*)d_in[1];   // (100, 512) f32
    const int*   T = (const int*)d_in[2];     // (256,) i32
    // d_in[3] = indices, unused
    float* ws = (float*)d_ws;
    float* rn        = ws;                    // 356
    float* IP        = ws + 512;              // 25600
    float* G         = ws + 26624;            // 65536
    float* loss_real = ws + 92160;            // 256
    float* psum      = ws + 92416;            // 16384  (end 108800 floats ~ 435 KB)
    float* out = (float*)d_out;

    norms_kernel<<<89, 256, 0, stream>>>(X, P, rn);
    dots_kernel<<<22720, 256, 0, stream>>>(X, P, rn, T, IP, G);
    pair_real_kernel<<<16448, 256, 0, stream>>>(IP, G, T, psum, loss_real);
    finalize_kernel<<<1, 256, 0, stream>>>(psum, loss_real, T, out);
}

// Round 3
// 94.695 us; speedup vs baseline: 1.1247x; 1.1247x over previous
//
#include <hip/hip_runtime.h>
#include <math.h>

#define N_ 256
#define C_ 100
#define D_ 512

__device__ inline float waveReduceSum(float v) {
    #pragma unroll
    for (int off = 32; off > 0; off >>= 1) v += __shfl_xor(v, off, 64);
    return v;
}
__device__ inline float waveReduceMax(float v) {
    #pragma unroll
    for (int off = 32; off > 0; off >>= 1) v = fmaxf(v, __shfl_xor(v, off, 64));
    return v;
}
__device__ inline float clip1(float x) { return fminf(fmaxf(x, -1.0f), 1.0f); }
__device__ inline float dot4(float4 a, float4 b) {
    return a.x*b.x + a.y*b.y + a.z*b.z + a.w*b.w;
}

// K1: all dots with norms fused in (no separate norms pass, no rn array).
//   wid < 6400  : i = wid/25, pg = wid%25 -> IP[i, 4*pg + j] for j=0..3
//   wid >= 6400 : q = wid-6400; i1 = q&255; dg = q>>8 in [0,64);
//                 i2_j = i1 + 4*dg + j + 1 -> G[i1,i2_j] (cross-class, i2<256 only)
// Each wave loads its a-row once (distributed over 64 lanes) and up to 4 b-rows,
// computes ||a||^2, ||b_j||^2, a.b_j in one pass, scales in the epilogue.
// Grid 5696 x 256 (4 waves/block), 22784 waves.
__global__ void dots_kernel(const float* __restrict__ X,
                            const float* __restrict__ P,
                            const int* __restrict__ T,
                            float* __restrict__ IP,
                            float* __restrict__ G) {
    int wid = blockIdx.x * 4 + (threadIdx.x >> 6);
    int lane = threadIdx.x & 63;

    const float4* a4;
    const float4* b4[4];
    float* dst[4];
    bool valid[4];

    if (wid < 6400) {
        int i = wid / 25, pg = wid - i * 25;
        a4 = (const float4*)(X + (size_t)i * D_);
        #pragma unroll
        for (int j = 0; j < 4; ++j) {
            int p = pg * 4 + j;                       // < 100 always (25*4 == 100)
            b4[j] = (const float4*)(P + (size_t)p * D_);
            dst[j] = IP + (size_t)i * C_ + p;
            valid[j] = true;
        }
    } else {
        int q = wid - 6400;
        int i1 = q & 255, dg = q >> 8;
        a4 = (const float4*)(X + (size_t)i1 * D_);
        int t1 = T[i1];
        #pragma unroll
        for (int j = 0; j < 4; ++j) {
            int i2 = i1 + dg * 4 + j + 1;
            bool v = (i2 < N_) && (T[i2 < N_ ? i2 : 0] != t1);
            int i2c = v ? i2 : 0;
            b4[j] = (const float4*)(X + (size_t)i2c * D_);
            dst[j] = G + (size_t)i1 * N_ + i2c;
            valid[j] = v;
        }
    }

    float4 a0 = a4[lane], a1 = a4[lane + 64];
    float ssa = dot4(a0, a0) + dot4(a1, a1);

    float4 b0[4], b1[4];
    #pragma unroll
    for (int j = 0; j < 4; ++j) {
        if (valid[j]) { b0[j] = b4[j][lane]; b1[j] = b4[j][lane + 64]; }
    }

    ssa = waveReduceSum(ssa);
    float sa = 3.0f / fmaxf(sqrtf(ssa), 1e-12f);

    #pragma unroll
    for (int j = 0; j < 4; ++j) {
        if (valid[j]) {
            float d  = dot4(a0, b0[j]) + dot4(a1, b1[j]);
            float sb = dot4(b0[j], b0[j]) + dot4(b1[j], b1[j]);
            d  = waveReduceSum(d);
            sb = waveReduceSum(sb);
            if (lane == 0)
                *dst[j] = d * sa * (3.0f / fmaxf(sqrtf(sb), 1e-12f));
        }
    }
}

// K2: fused pair-loss + real-loss. 4 pairs per wave sharing the i1 IP row.
//   blocks [0, 4096): wave gw = blk*4+w handles pids gw*4 .. gw*4+3
//                     (i1 = pid>>8 constant within the wave's 4 pids)
//   blocks [4096, 4112): wave handles 4 real rows.
__global__ void pair_real_kernel(const float* __restrict__ IP,
                                 const float* __restrict__ G,
                                 const int* __restrict__ T,
                                 float* __restrict__ psum,
                                 float* __restrict__ loss_real) {
    int w = threadIdx.x >> 6, lane = threadIdx.x & 63;
    int blk = blockIdx.x;
    bool vb = lane < (C_ - 64);                       // lane < 36
    if (blk < 4096) {
        int pid0 = (blk * 4 + w) * 4;                 // base pid, [0, 65536)
        int i1 = pid0 >> 8;
        int i2base = pid0 & 255;
        const float* ip1 = IP + (size_t)i1 * C_;
        float r1a = ip1[lane];
        float r1b = vb ? ip1[lane + 64] : 0.0f;
        int t1 = T[i1];
        float ip1t1 = (t1 < 64) ? __shfl(r1a, t1, 64) : __shfl(r1b, t1 - 64, 64);
        float contrib = 0.0f;
        #pragma unroll
        for (int k = 0; k < 4; ++k) {
            int i2 = i2base + k;
            if (i2 <= i1) continue;                   // wave-uniform
            int t2 = T[i2];
            if (t2 == t1) continue;                   // wave-uniform
            const float* ip2 = IP + (size_t)i2 * C_;
            float r2a = ip2[lane];
            float r2b = vb ? ip2[lane + 64] : 0.0f;
            float g = G[(size_t)i1 * N_ + i2];
            float ip1t2 = (t2 < 64) ? __shfl(r1a, t2, 64) : __shfl(r1b, t2 - 64, 64);
            float ip2t1 = (t1 < 64) ? __shfl(r2a, t1, 64) : __shfl(r2b, t1 - 64, 64);
            float ip2t2 = (t2 < 64) ? __shfl(r2a, t2, 64) : __shfl(r2b, t2 - 64, 64);
            float X1P1 = clip1(ip1t1), X1P2 = clip1(ip1t2);
            float X2P1 = clip1(ip2t1), X2P2 = clip1(ip2t2);
            float num = X2P2 - X2P1;
            float den = num + X1P1 - X1P2;
            float lam = fminf(fmaxf(num / den, 0.3f), 0.7f);
            float oml = 1.0f - lam;
            float wn2 = 9.0f * (lam*lam + oml*oml) + 2.0f * lam * oml * g;
            float s = 3.0f / fmaxf(sqrtf(fmaxf(wn2, 0.0f)), 1e-12f);
            float s2 = 2.0f * s;
            float e_a = s2 * (lam * r1a + oml * r2a);
            float e_b = vb ? s2 * (lam * r1b + oml * r2b) : -INFINITY;
            float mx = waveReduceMax(fmaxf(e_a, e_b));
            float sum = expf(e_a - mx) + (vb ? expf(e_b - mx) : 0.0f);
            sum = waveReduceSum(sum);
            float LSE = mx + logf(sum);
            float ec1 = (t1 < 64) ? __shfl(e_a, t1, 64) : __shfl(e_b, t1 - 64, 64);
            float ec2 = (t2 < 64) ? __shfl(e_a, t2, 64) : __shfl(e_b, t2 - 64, 64);
            contrib += LSE - lam * ec1 - oml * ec2;
        }
        __shared__ float ssum[4];
        if (lane == 0) ssum[w] = contrib;
        __syncthreads();
        if (threadIdx.x == 0) psum[blk] = ssum[0] + ssum[1] + ssum[2] + ssum[3];
    } else {
        int base = (blk - 4096) * 16 + w * 4;         // 16 blocks x 4 waves x 4 rows = 256
        #pragma unroll
        for (int k = 0; k < 4; ++k) {
            int i = base + k;
            const float* ip = IP + (size_t)i * C_;
            float e_a = 2.0f * ip[lane];
            float e_b = vb ? 2.0f * ip[lane + 64] : -INFINITY;
            float mx = waveReduceMax(fmaxf(e_a, e_b));
            float sum = expf(e_a - mx) + (vb ? expf(e_b - mx) : 0.0f);
            sum = waveReduceSum(sum);
            float LSE = mx + logf(sum);
            if (lane == 0) loss_real[i] = LSE - 2.0f * ip[T[i]];
        }
    }
}

// K3: final reduce. 1 block x 256. Pair count via class histogram:
// diff_count = 32640 - sum_c n_c(n_c-1)/2.
__global__ void finalize_kernel(const float* __restrict__ psum,
                                const float* __restrict__ loss_real,
                                const int* __restrict__ T,
                                float* __restrict__ out) {
    __shared__ int hist[C_];
    int t = threadIdx.x;
    if (t < C_) hist[t] = 0;
    __syncthreads();
    atomicAdd(&hist[T[t]], 1);
    __syncthreads();
    float a = loss_real[t];
    #pragma unroll
    for (int k = 0; k < 16; ++k) a += psum[t + k * 256];
    float same = 0.0f;
    if (t < C_) { float n = (float)hist[t]; same = 0.5f * n * (n - 1.0f); }
    float ra = waveReduceSum(a), rs = waveReduceSum(same);
    __shared__ float s1[4], s2[4];
    int w = t >> 6, lane = t & 63;
    if (lane == 0) { s1[w] = ra; s2[w] = rs; }
    __syncthreads();
    if (t == 0) {
        float tot = s1[0] + s1[1] + s1[2] + s1[3];
        float sm  = s2[0] + s2[1] + s2[2] + s2[3];
        float cnt = (float)N_ + (32640.0f - sm);
        out[0] = tot / cnt;
    }
}

extern "C" void kernel_launch(void* const* d_in, const int* in_sizes, int n_in,
                              void* d_out, int out_size, void* d_ws, size_t ws_size,
                              hipStream_t stream) {
    const float* X = (const float*)d_in[0];   // (256, 512) f32
    const float* P = (const float*)d_in[1];   // (100, 512) f32
    const int*   T = (const int*)d_in[2];     // (256,) i32
    // d_in[3] = indices, unused
    float* ws = (float*)d_ws;
    float* IP        = ws;                    // 25600
    float* G         = ws + 25600;            // 65536
    float* psum      = ws + 91136;            // 4096
    float* loss_real = ws + 95232;            // 256   (total ~382 KB)
    float* out = (float*)d_out;

    dots_kernel<<<5696, 256, 0, stream>>>(X, P, T, IP, G);
    pair_real_kernel<<<4112, 256, 0, stream>>>(IP, G, T, psum, loss_real);
    finalize_kernel<<<1, 256, 0, stream>>>(psum, loss_real, T, out);
}